// Round 3
// 218.148 us; speedup vs baseline: 1.0031x; 1.0031x over previous
//
#include <hip/hip_runtime.h>
#include <math.h>

#define TOKENS 16384
#define HIDDEN 2048
#define NEXP   64
#define MT     32                  // tokens per block
#define NBLK   (TOKENS / MT)       // 512

#define GATES_OFF (TOKENS * 2)
#define SEL_OFF   (GATES_OFF + TOKENS * NEXP)
#define Z_OFF     (SEL_OFF + TOKENS * 2)

#define WIMG_BYTES (NEXP * HIDDEN * 2 * 2)   // 512 KB: fp16 wh+wl fragment image

typedef __attribute__((ext_vector_type(8))) _Float16 f16x8;
typedef __attribute__((ext_vector_type(4))) float    f32x4;

__device__ __forceinline__ float wave_sum64(float v) {
    #pragma unroll
    for (int s = 1; s < 64; s <<= 1) v += __shfl_xor(v, s, 64);
    return v;
}

// ---------------------------------------------------------------------------
// Setup: convert w [64,2048] fp32 -> fp16 (hi, lo*4096) fragment image in ws.
// Image: [chunk 32][r 1024] of 16-B slots; r = eh*512 + term*256 + kh*128 +
// nt*64 + lane. Slot lane l: n = l&15, klocal = (l>>4)*8 + j (verified
// 16x16x32 B-operand layout). [unchanged from verified R3/R4 kernel]
// ---------------------------------------------------------------------------
__global__ __launch_bounds__(256) void wconvert(
    const float* __restrict__ w, uint4* __restrict__ wimg)
{
    const int s = blockIdx.x * 256 + threadIdx.x;     // 0..32767
    const int c    = s >> 10;
    const int r    = s & 1023;
    const int l    = r & 63;
    const int nt   = (r >> 6) & 1;
    const int kh   = (r >> 7) & 1;
    const int term = (r >> 8) & 1;
    const int eh   = (r >> 9) & 1;
    const int e = eh * 32 + nt * 16 + (l & 15);
    const int k = c * 64 + kh * 32 + (l >> 4) * 8;

    const float* src = w + (size_t)e * HIDDEN + k;
    union { _Float16 f[8]; uint4 u; } o;
    #pragma unroll
    for (int j = 0; j < 8; ++j) {
        const float v = src[j];
        const _Float16 h = (_Float16)v;
        o.f[j] = (term == 0) ? h : (_Float16)((v - (float)h) * 4096.f);
    }
    wimg[s] = o.u;
}

// ---------------------------------------------------------------------------
// fp32 -> (hi, lo*4096) fp16x8 split of 8 floats (two float4)
// ---------------------------------------------------------------------------
__device__ __forceinline__ void cvt_split(const float4 a, const float4 b,
                                          f16x8& hi, f16x8& lo) {
    union { _Float16 f[8]; f16x8 v; } H, L;
    #pragma unroll
    for (int j = 0; j < 4; ++j) {
        const float s0 = (&a.x)[j];
        const float s1 = (&b.x)[j];
        const _Float16 h0 = (_Float16)s0;
        const _Float16 h1 = (_Float16)s1;
        H.f[j]     = h0;
        H.f[j + 4] = h1;
        L.f[j]     = (_Float16)((s0 - (float)h0) * 4096.f);
        L.f[j + 4] = (_Float16)((s1 - (float)h1) * 4096.f);
    }
    hi = H.v; lo = L.v;
}

// ---------------------------------------------------------------------------
// Register pipeline buffer: one 32-k step of A (raw fp32) + B (fp16 frags).
// All accesses use compile-time indices (fully unrolled) -> stays in VGPRs.
// ---------------------------------------------------------------------------
struct Pipe {
    float4 ra0, ra1, ra2, ra3;   // raw x: 2 rows x 8 floats
    f16x8  bh[4], bl[4];         // B frags: g = eh*2+nt, hi/lo terms
};

__device__ __forceinline__ void loadA(Pipe& P, const float* ax0,
                                      const float* ax1, int s) {
    P.ra0 = *(const float4*)(ax0 + s * 32);
    P.ra1 = *(const float4*)(ax0 + s * 32 + 4);
    P.ra2 = *(const float4*)(ax1 + s * 32);
    P.ra3 = *(const float4*)(ax1 + s * 32 + 4);
}

__device__ __forceinline__ void loadB(Pipe& P, const uint4* wB, int s) {
    const uint4* p = wB + (s >> 1) * 1024 + (s & 1) * 128;
    P.bh[0] = *(const f16x8*)(p);          // eh0 nt0 hi
    P.bh[1] = *(const f16x8*)(p + 64);     // eh0 nt1 hi
    P.bh[2] = *(const f16x8*)(p + 512);    // eh1 nt0 hi
    P.bh[3] = *(const f16x8*)(p + 576);    // eh1 nt1 hi
    P.bl[0] = *(const f16x8*)(p + 256);
    P.bl[1] = *(const f16x8*)(p + 320);
    P.bl[2] = *(const f16x8*)(p + 768);
    P.bl[3] = *(const f16x8*)(p + 832);
}

__device__ __forceinline__ void domfma(const Pipe& P,
                                       const f16x8 Ah0, const f16x8 Ah1,
                                       const f16x8 Al0, const f16x8 Al1,
                                       f32x4 (&acc0)[2][4], f32x4 (&acc1)[2][4]) {
    #pragma unroll
    for (int g = 0; g < 4; ++g) {
        acc0[0][g] = __builtin_amdgcn_mfma_f32_16x16x32_f16(Ah0, P.bh[g], acc0[0][g], 0, 0, 0);
        acc1[0][g] = __builtin_amdgcn_mfma_f32_16x16x32_f16(Ah0, P.bl[g], acc1[0][g], 0, 0, 0);
        acc1[0][g] = __builtin_amdgcn_mfma_f32_16x16x32_f16(Al0, P.bh[g], acc1[0][g], 0, 0, 0);
        acc0[1][g] = __builtin_amdgcn_mfma_f32_16x16x32_f16(Ah1, P.bh[g], acc0[1][g], 0, 0, 0);
        acc1[1][g] = __builtin_amdgcn_mfma_f32_16x16x32_f16(Ah1, P.bl[g], acc1[1][g], 0, 0, 0);
        acc1[1][g] = __builtin_amdgcn_mfma_f32_16x16x32_f16(Al1, P.bh[g], acc1[1][g], 0, 0, 0);
    }
}

// ---------------------------------------------------------------------------
// R6 restructure: barrier-free main loop.
// 512 blocks x 256 thr (4 waves). Wave wv: 32 tokens x ALL 64 experts x
// k in [wv*512, wv*512+512) -- 16 steps of 32k. A fragments loaded DIRECTLY
// global->VGPR in native 16x16x32 fragment pattern (lane l: row l&15,
// k (l>>4)*8..+8, 32 B contiguous/lane). B fragments global->VGPR from wimg
// (lane-linear, coalesced, L2-resident). Double-buffered register prefetch,
// depth ~2 steps; NO __syncthreads in the loop. Single barrier before
// epilogue; 4 k-partials summed via LDS [4][32][66]; routing math unchanged.
// ---------------------------------------------------------------------------
__global__ __launch_bounds__(256, 2) void router_main(
    const float* __restrict__ x, const uint4* __restrict__ wimg,
    float* __restrict__ out, float* __restrict__ zpartial)
{
    __shared__ __align__(16) float lg[4][32 * 66];   // 33792 B k-partial logits
    __shared__ float zred[4];

    const int tid  = threadIdx.x;
    const int wv   = __builtin_amdgcn_readfirstlane(tid >> 6);
    const int lane = tid & 63;
    const int t0   = blockIdx.x * MT;

    // A source pointers: lane reads rows t0 + mt*16 + (lane&15),
    // k = wv*512 + s*32 + (lane>>4)*8  (8 consecutive floats = 2 float4)
    const float* ax0 = x + (size_t)(t0 + (lane & 15)) * HIDDEN
                         + wv * 512 + (lane >> 4) * 8;
    const float* ax1 = ax0 + 16 * HIDDEN;

    // B source: this wave's k range; per step s (32k): c = wv*8 + (s>>1),
    // kh = s&1.  frag(g,term) at eh*512 + term*256 + nt*64, g = eh*2+nt.
    const uint4* wB = wimg + wv * 8192 + lane;

    f32x4 acc0[2][4], acc1[2][4];
    #pragma unroll
    for (int mt = 0; mt < 2; ++mt)
        #pragma unroll
        for (int g = 0; g < 4; ++g) { acc0[mt][g] = (f32x4)0.f; acc1[mt][g] = (f32x4)0.f; }

    Pipe PA, PB;
    f16x8 Ah0, Ah1, Al0, Al1;

    // prologue: fill both pipeline buffers
    loadA(PA, ax0, ax1, 0); loadB(PA, wB, 0);
    loadA(PB, ax0, ax1, 1); loadB(PB, wB, 1);

    #pragma unroll
    for (int s = 0; s < 16; s += 2) {
        // even step s: consume PA, refill for s+2
        cvt_split(PA.ra0, PA.ra1, Ah0, Al0);
        cvt_split(PA.ra2, PA.ra3, Ah1, Al1);
        if (s + 2 < 16) loadA(PA, ax0, ax1, s + 2);
        domfma(PA, Ah0, Ah1, Al0, Al1, acc0, acc1);
        if (s + 2 < 16) loadB(PA, wB, s + 2);

        // odd step s+1: consume PB, refill for s+3
        cvt_split(PB.ra0, PB.ra1, Ah0, Al0);
        cvt_split(PB.ra2, PB.ra3, Ah1, Al1);
        if (s + 3 < 16) loadA(PB, ax0, ax1, s + 3);
        domfma(PB, Ah0, Ah1, Al0, Al1, acc0, acc1);
        if (s + 3 < 16) loadB(PB, wB, s + 3);
    }

    // ---- epilogue: write this wave's k-partial logits (hi + lo/4096) ----
    #pragma unroll
    for (int mt = 0; mt < 2; ++mt)
        #pragma unroll
        for (int g = 0; g < 4; ++g)
            #pragma unroll
            for (int r = 0; r < 4; ++r) {
                const int tok = mt * 16 + (lane >> 4) * 4 + r;      // C/D row
                const int e   = (g >> 1) * 32 + (g & 1) * 16 + (lane & 15);
                lg[wv][tok * 66 + e] = acc0[mt][g][r] + acc1[mt][g][r] * (1.f / 4096.f);
            }
    __syncthreads();

    // ---- routing (R1-verified math): wave handles 8 tokens, lane = expert ----
    float zsum = 0.f;
    for (int tt = 0; tt < 8; ++tt) {
        const int t = wv * 8 + tt;
        const int li = t * 66 + lane;
        const float v = lg[0][li] + lg[1][li] + lg[2][li] + lg[3][li];

        float bv = v; int bi = lane;
        #pragma unroll
        for (int s = 1; s < 64; s <<= 1) {
            const float ov = __shfl_xor(bv, s, 64);
            const int   oi = __shfl_xor(bi, s, 64);
            if (ov > bv || (ov == bv && oi < bi)) { bv = ov; bi = oi; }
        }
        const float max1 = bv; const int s1 = bi;

        const float e1 = expf(v - max1);
        const float sume = wave_sum64(e1);
        out[GATES_OFF + (size_t)(t0 + t) * NEXP + lane] = e1 / sume;
        const float lse = max1 + logf(sume);
        zsum += lse * lse;

        const bool mask1 = (max1 - v) > 0.02f * fmaxf(fabsf(v), max1);
        const float sum1 = wave_sum64(mask1 ? 0.f : e1);

        float bv2 = (lane == s1) ? -INFINITY : v; int bi2 = lane;
        #pragma unroll
        for (int s = 1; s < 64; s <<= 1) {
            const float ov = __shfl_xor(bv2, s, 64);
            const int   oi = __shfl_xor(bi2, s, 64);
            if (ov > bv2 || (ov == bv2 && oi < bi2)) { bv2 = ov; bi2 = oi; }
        }
        const float max2 = bv2; const int s2 = bi2;

        const bool mask2 = (max2 - v) > 0.02f * fmaxf(fabsf(v), max2);
        const float p2v = (mask2 || lane == s1) ? 0.f : expf(v - max2);
        const float sum2 = wave_sum64(p2v);

        if (lane == 0) {
            const size_t trow = (size_t)(t0 + t) * 2;
            out[trow + 0] = 1.f / sum1;
            out[trow + 1] = 1.f / sum2;
            out[SEL_OFF + trow + 0] = (float)s1;
            out[SEL_OFF + trow + 1] = (float)s2;
        }
    }

    if (lane == 0) zred[wv] = zsum;
    __syncthreads();
    if (tid == 0)
        zpartial[blockIdx.x] = zred[0] + zred[1] + zred[2] + zred[3];
}

__global__ __launch_bounds__(256) void zfinal(
    const float* __restrict__ zpartial, float* __restrict__ out)
{
    const int tid = threadIdx.x;                 // 512 partials, 256 threads
    float v = zpartial[tid] + zpartial[tid + 256];
    v = wave_sum64(v);
    __shared__ float red[4];
    if ((tid & 63) == 0) red[tid >> 6] = v;
    __syncthreads();
    if (tid == 0) {
        const float tot = red[0] + red[1] + red[2] + red[3];
        out[Z_OFF] = 0.001f * (tot / (float)TOKENS);
    }
}

extern "C" void kernel_launch(void* const* d_in, const int* in_sizes, int n_in,
                              void* d_out, int out_size, void* d_ws, size_t ws_size,
                              hipStream_t stream) {
    const float* x = (const float*)d_in[0];   // [16384, 2048] fp32
    const float* w = (const float*)d_in[1];   // [64, 2048] fp32
    float* out = (float*)d_out;               // mult(32768) | gates(1048576) | sel(32768) | z(1)

    uint4* wimg     = (uint4*)d_ws;                               // 512 KB
    float* zpartial = (float*)((char*)d_ws + WIMG_BYTES);         // 512 floats

    wconvert<<<128, 256, 0, stream>>>(w, wimg);
    router_main<<<NBLK, 256, 0, stream>>>(x, wimg, out, zpartial);
    zfinal<<<1, 256, 0, stream>>>(zpartial, out);
}